// Round 3
// baseline (364.513 us; speedup 1.0000x reference)
//
#include <hip/hip_runtime.h>
#include <hip/hip_bf16.h>

#define NN 128
#define TT 256
#define EE 6
#define DD 10
#define TE (TT*EE)          // 1536 floats per j-slice
#define C1 15               // input1 inner dim: 1+E+E+2
#define NBLK2 4096          // pair_all grid: 4 waves/block, 1 (i,j) pair/wave

// Kernel 0: w[j*TE + t*E + e] = 1 / input1[j,t,7+e]^2 ; zero completion counter.
__global__ void prep_w(const float* __restrict__ input1, float* __restrict__ w,
                       unsigned int* __restrict__ cnt) {
    int idx = blockIdx.x * 256 + threadIdx.x;      // over N*T*E = 196608
    if (idx == 0) *cnt = 0u;
    if (idx < NN * TE) {
        int f = idx % TE;
        int j = idx / TE;
        int t = f / EE, e = f % EE;
        float v = input1[(j * TT + t) * C1 + 1 + EE + e];
        w[idx] = 1.0f / (v * v);
    }
}

// Kernel 1 (fused): one (i,j) pair per wave. 1536 floats = 384 float4 =
// 64 lanes x 6. All 18 loads issued up-front for MLP; wave shuffle reduce;
// last block computes the final scalar (no extra dispatch, no memset).
__launch_bounds__(256)
__global__ void pair_all(const float* __restrict__ yij,
                         const float* __restrict__ yi,
                         const float* __restrict__ w,
                         const float* __restrict__ samples,
                         float* __restrict__ raw,
                         unsigned int* __restrict__ cnt,
                         float* __restrict__ out) {
    const int tid  = threadIdx.x;
    const int wv   = tid >> 6;
    const int lane = tid & 63;
    const int p    = blockIdx.x * 4 + wv;      // pair index 0..16383
    const int j    = p & (NN - 1);             // i = p >> 7 implicit: p == i*NN+j

    const float4* a  = (const float4*)(yij + (size_t)p * TE);
    const float4* m4 = (const float4*)(yi  + (size_t)j * TE);
    const float4* w4 = (const float4*)(w   + (size_t)j * TE);

    float4 x[6], mm[6], ww[6];
#pragma unroll
    for (int m = 0; m < 6; ++m) x[m]  = a[lane + 64 * m];
#pragma unroll
    for (int m = 0; m < 6; ++m) mm[m] = m4[lane + 64 * m];
#pragma unroll
    for (int m = 0; m < 6; ++m) ww[m] = w4[lane + 64 * m];

    float s = 0.0f;
#pragma unroll
    for (int m = 0; m < 6; ++m) {
        float d0 = x[m].x - mm[m].x; s += d0 * d0 * ww[m].x;
        float d1 = x[m].y - mm[m].y; s += d1 * d1 * ww[m].y;
        float d2 = x[m].z - mm[m].z; s += d2 * d2 * ww[m].z;
        float d3 = x[m].w - mm[m].w; s += d3 * d3 * ww[m].w;
    }
#pragma unroll
    for (int off = 32; off > 0; off >>= 1) s += __shfl_down(s, off);
    if (lane == 0) raw[p] = s;

    // ---- last-block-done finalize ----
    __shared__ int isLast;
    __syncthreads();
    if (tid == 0) {
        __threadfence();             // release raw writes device-wide
        unsigned int old = atomicAdd(cnt, 1u);
        isLast = (old == NBLK2 - 1) ? 1 : 0;
    }
    __syncthreads();
    if (!isLast) return;
    __threadfence();                 // acquire all blocks' raw writes

    __shared__ float smp[NN * DD];   // 1280 floats
    for (int q = tid; q < NN * DD; q += 256) smp[q] = samples[q];
    __syncthreads();

    float acc = 0.0f;
    for (int it = 0; it < 64; ++it) {
        const int pp = it * 256 + tid;       // coalesced over raw[pp]
        const int i  = pp >> 7, jj = pp & 127;
        float S = 0.0f;
#pragma unroll
        for (int d = 0; d < DD; ++d) {
            float dd = smp[jj * DD + d] - smp[i * DD + d];
            S += dd * dd;
        }
        S *= (1.0f / DD);
        float sec = (raw[pp] + raw[jj * NN + i]) * (0.5f / (TE * 10.0f));
        acc += fabsf(S - sec);
    }
#pragma unroll
    for (int off = 32; off > 0; off >>= 1) acc += __shfl_down(acc, off);
    __shared__ float ls[4];
    if ((tid & 63) == 0) ls[tid >> 6] = acc;
    __syncthreads();
    if (tid == 0)
        out[0] = (ls[0] + ls[1] + ls[2] + ls[3]) * (1.0f / (NN * NN));
}

extern "C" void kernel_launch(void* const* d_in, const int* in_sizes, int n_in,
                              void* d_out, int out_size, void* d_ws, size_t ws_size,
                              hipStream_t stream) {
    // inputs: merged, y_pred_i, y_pred_ij, input1, samples, labels
    const float* y_pred_i  = (const float*)d_in[1];
    const float* y_pred_ij = (const float*)d_in[2];
    const float* input1    = (const float*)d_in[3];
    const float* samples   = (const float*)d_in[4];
    float* out = (float*)d_out;

    // ws layout: w (N*TE floats) | raw (N*N floats) | counter (1 uint)
    float* w   = (float*)d_ws;
    float* raw = w + (size_t)NN * TE;
    unsigned int* cnt = (unsigned int*)(raw + (size_t)NN * NN);

    prep_w<<<(NN * TE + 255) / 256, 256, 0, stream>>>(input1, w, cnt);

    pair_all<<<NBLK2, 256, 0, stream>>>(y_pred_ij, y_pred_i, w,
                                        samples, raw, cnt, out);
}

// Round 4
// 164.528 us; speedup vs baseline: 2.2155x; 2.2155x over previous
//
#include <hip/hip_runtime.h>
#include <hip/hip_bf16.h>

#define NN 128
#define TT 256
#define EE 6
#define DD 10
#define TE (TT*EE)          // 1536 floats per j-slice
#define C1 15               // input1 inner dim: 1+E+E+2

// Kernel 0: w[j*TE + t*E + e] = 1 / input1[j,t,7+e]^2
__global__ void prep_w(const float* __restrict__ input1, float* __restrict__ w) {
    int idx = blockIdx.x * 256 + threadIdx.x;      // over N*T*E = 196608
    if (idx < NN * TE) {
        int f = idx % TE;
        int j = idx / TE;
        int t = f / EE, e = f % EE;
        float v = input1[(j * TT + t) * C1 + 1 + EE + e];
        w[idx] = 1.0f / (v * v);
    }
}

// Kernel 1: raw[p] = sum_{t,e} (yij[p,t,e]-yi[j,t,e])^2 * w[j,t,e],  p = i*NN+j.
// One (i,j) pair per wave, 4 waves/block, 4096 blocks. 18 independent float4
// loads issued up-front (MLP), wave shuffle reduce, one store. NO cross-block
// protocol — dispatch boundary provides coherence (R2/R3 lesson: per-block
// device-scope fence + same-address atomic across 8 XCDs costs ~60ns each,
// serialized = 250us at 4096 blocks).
__launch_bounds__(256)
__global__ void pair_reduce(const float* __restrict__ yij,
                            const float* __restrict__ yi,
                            const float* __restrict__ w,
                            float* __restrict__ raw) {
    const int tid  = threadIdx.x;
    const int wv   = tid >> 6;
    const int lane = tid & 63;
    const int p    = blockIdx.x * 4 + wv;      // pair index 0..16383
    const int j    = p & (NN - 1);

    const float4* a  = (const float4*)(yij + (size_t)p * TE);
    const float4* m4 = (const float4*)(yi  + (size_t)j * TE);
    const float4* w4 = (const float4*)(w   + (size_t)j * TE);

    float4 x[6], mm[6], ww[6];
#pragma unroll
    for (int m = 0; m < 6; ++m) x[m]  = a[lane + 64 * m];
#pragma unroll
    for (int m = 0; m < 6; ++m) mm[m] = m4[lane + 64 * m];
#pragma unroll
    for (int m = 0; m < 6; ++m) ww[m] = w4[lane + 64 * m];

    float s = 0.0f;
#pragma unroll
    for (int m = 0; m < 6; ++m) {
        float d0 = x[m].x - mm[m].x; s += d0 * d0 * ww[m].x;
        float d1 = x[m].y - mm[m].y; s += d1 * d1 * ww[m].y;
        float d2 = x[m].z - mm[m].z; s += d2 * d2 * ww[m].z;
        float d3 = x[m].w - mm[m].w; s += d3 * d3 * ww[m].w;
    }
#pragma unroll
    for (int off = 32; off > 0; off >>= 1) s += __shfl_down(s, off);
    if (lane == 0) raw[p] = s;
}

// Kernel 2: single block, 1024 threads. Stage raw into LDS with +1 padded
// row (stride 129) so the transposed raw[j,i] read is conflict-free.
// Writes out[0] directly — no memset, no atomic.
__launch_bounds__(1024)
__global__ void finalize(const float* __restrict__ raw,
                         const float* __restrict__ samples,
                         float* __restrict__ out) {
    __shared__ float r[NN * (NN + 1)];   // 66048 B, padded stride 129
    __shared__ float smp[NN * DD];       // 1280 floats
    __shared__ float ls[16];
    const int tid = threadIdx.x;

#pragma unroll
    for (int it = 0; it < 16; ++it) {
        int pp = it * 1024 + tid;        // coalesced global read
        r[(pp >> 7) * (NN + 1) + (pp & 127)] = raw[pp];
    }
    for (int q = tid; q < NN * DD; q += 1024) smp[q] = samples[q];
    __syncthreads();

    float acc = 0.0f;
#pragma unroll
    for (int it = 0; it < 16; ++it) {
        const int pp = it * 1024 + tid;
        const int i  = pp >> 7, jj = pp & 127;
        float S = 0.0f;
#pragma unroll
        for (int d = 0; d < DD; ++d) {
            float dd = smp[jj * DD + d] - smp[i * DD + d];
            S += dd * dd;
        }
        S *= (1.0f / DD);
        float sec = (r[i * (NN + 1) + jj] + r[jj * (NN + 1) + i])
                    * (0.5f / (TE * 10.0f));
        acc += fabsf(S - sec);
    }
#pragma unroll
    for (int off = 32; off > 0; off >>= 1) acc += __shfl_down(acc, off);
    if ((tid & 63) == 0) ls[tid >> 6] = acc;
    __syncthreads();
    if (tid == 0) {
        float t = 0.0f;
#pragma unroll
        for (int q = 0; q < 16; ++q) t += ls[q];
        out[0] = t * (1.0f / (NN * NN));
    }
}

extern "C" void kernel_launch(void* const* d_in, const int* in_sizes, int n_in,
                              void* d_out, int out_size, void* d_ws, size_t ws_size,
                              hipStream_t stream) {
    // inputs: merged, y_pred_i, y_pred_ij, input1, samples, labels
    const float* y_pred_i  = (const float*)d_in[1];
    const float* y_pred_ij = (const float*)d_in[2];
    const float* input1    = (const float*)d_in[3];
    const float* samples   = (const float*)d_in[4];
    float* out = (float*)d_out;

    // ws layout: w (N*TE floats) | raw (N*N floats)
    float* w   = (float*)d_ws;
    float* raw = w + (size_t)NN * TE;

    prep_w<<<(NN * TE + 255) / 256, 256, 0, stream>>>(input1, w);
    pair_reduce<<<(NN * NN) / 4, 256, 0, stream>>>(y_pred_ij, y_pred_i, w, raw);
    finalize<<<1, 1024, 0, stream>>>(raw, samples, out);
}